// Round 6
// baseline (467.830 us; speedup 1.0000x reference)
//
#include <hip/hip_runtime.h>
#include <hip/hip_bf16.h>
#include <stdint.h>

// Problem constants
#define B_  8
#define S_  2048
#define D_  768
#define H_  12
#define HD_ 64
#define BH_ (B_*H_)   // 96
#define M_  (B_*S_)   // 16384

typedef __bf16 bf16;
typedef __bf16 bf16x8 __attribute__((ext_vector_type(8)));
typedef __bf16 bf16x4 __attribute__((ext_vector_type(4)));
typedef short  short4v __attribute__((ext_vector_type(4)));
typedef float  f32x4  __attribute__((ext_vector_type(4)));

// 1/(8+1e-6) * log2(e): Q pre-scale so softmax numerator = exp2(QK)
#define QSCALE_LOG2E 0.18033685756909415f

// raw v_exp_f32 (base-2 exponential)
#define EXP2F(x) __builtin_amdgcn_exp2f(x)

// 16x16x16 bf16 MFMA: A-layout == C/D-layout-transposed, the key identity.
#if __has_builtin(__builtin_amdgcn_mfma_f32_16x16x16bf16_1k)
static __device__ inline f32x4 mfma16(bf16x4 a, bf16x4 b, f32x4 c) {
  return __builtin_amdgcn_mfma_f32_16x16x16bf16_1k(
      __builtin_bit_cast(short4v, a), __builtin_bit_cast(short4v, b), c, 0, 0, 0);
}
#else
static __device__ inline f32x4 mfma16(bf16x4 a, bf16x4 b, f32x4 c) {
  bf16 z = (bf16)0.f;
  bf16x8 a8 = {a[0], a[1], a[2], a[3], z, z, z, z};
  bf16x8 b8 = {b[0], b[1], b[2], b[3], z, z, z, z};
  return __builtin_amdgcn_mfma_f32_16x16x32_bf16(a8, b8, c, 0, 0, 0);
}
#endif

// ---------------------------------------------------------------------------
// fp32 -> bf16 elementwise convert, 8 elems/thread
// ---------------------------------------------------------------------------
__global__ __launch_bounds__(256) void f2b(const float* __restrict__ src,
                                           bf16* __restrict__ dst, int n) {
  int i = (blockIdx.x * 256 + threadIdx.x) * 8;
  if (i >= n) return;
  float4 a = *(const float4*)(src + i);
  float4 b = *(const float4*)(src + i + 4);
  bf16 o[8] = {(bf16)a.x, (bf16)a.y, (bf16)a.z, (bf16)a.w,
               (bf16)b.x, (bf16)b.y, (bf16)b.z, (bf16)b.w};
  *(uint4*)(dst + i) = *(const uint4*)o;
}

// ---------------------------------------------------------------------------
// 64x64-tile transpose + fp32->bf16: src f32 [mat][R][C] -> dst bf16 [mat][C][R]
// ---------------------------------------------------------------------------
__global__ __launch_bounds__(256) void transpose64_f2b(const float* __restrict__ src,
                                                       bf16* __restrict__ dst,
                                                       int R, int C) {
  __shared__ bf16 t[64][72];
  int mat = blockIdx.z;
  const float* s = src + (size_t)mat * R * C;
  bf16* d = dst + (size_t)mat * C * R;
  int r0 = blockIdx.x * 64, c0 = blockIdx.y * 64;
  int tid = threadIdx.x;
  #pragma unroll
  for (int it = 0; it < 4; ++it) {
    int i = (tid >> 4) + it * 16;
    int j = (tid & 15) * 4;
    float4 v = *(const float4*)(s + (size_t)(r0 + i) * C + c0 + j);
    t[j + 0][i] = (bf16)v.x; t[j + 1][i] = (bf16)v.y;
    t[j + 2][i] = (bf16)v.z; t[j + 3][i] = (bf16)v.w;
  }
  __syncthreads();
  #pragma unroll
  for (int it = 0; it < 4; ++it) {
    int i = (tid >> 4) + it * 16;
    int j = (tid & 15) * 4;
    bf16* p = d + (size_t)(c0 + i) * R + r0 + j;
    p[0] = t[i][j]; p[1] = t[i][j + 1]; p[2] = t[i][j + 2]; p[3] = t[i][j + 3];
  }
}

// ---------------------------------------------------------------------------
// Pack bq|bk|bv (fp32) into one 2304-element fp32 bias vector
// ---------------------------------------------------------------------------
__global__ void pack_bias(const float* __restrict__ bq, const float* __restrict__ bk,
                          const float* __restrict__ bv, float* __restrict__ ball) {
  int i = blockIdx.x * 256 + threadIdx.x;
  if (i < 2304) {
    float v = (i < 768) ? bq[i] : (i < 1536 ? bk[i - 768] : bv[i - 1536]);
    ball[i] = v;
  }
}

// ---------------------------------------------------------------------------
// GEMM: C[M,N] = A[M,K](bf16) * Bt[N,K]^T(bf16) + bias[N](fp32)
// 128x128 tile, BK=32, 256 threads (4 waves, 2x2), mfma_f32_16x16x32_bf16.
// MODE 0: fp32 row-major C. MODE 1: scatter Q (pre-scaled)/K to [B,H,S,64]
//         and V to V^T layout [bh][64][S] (bf16), all with bias.
// ---------------------------------------------------------------------------
template <int MODE>
__global__ __launch_bounds__(256, 2) void gemm_bt(
    const bf16* __restrict__ A, const bf16* __restrict__ Bt,
    const float* __restrict__ bias, float* __restrict__ C,
    bf16* __restrict__ Qo, bf16* __restrict__ Ko, bf16* __restrict__ Vo,
    int Mdim, int Ndim, int Kdim)
{
  __shared__ bf16 As[128 * 40];
  __shared__ bf16 Bs[128 * 40];
  int tid = threadIdx.x;
  int wave = tid >> 6, lane = tid & 63;
  int wm = wave & 1, wn = wave >> 1;
  int m0 = blockIdx.x * 128, n0 = blockIdx.y * 128;
  int lm = lane & 15, lq = lane >> 4;

  f32x4 zero = {0.f, 0.f, 0.f, 0.f};
  f32x4 acc[4][4];
  #pragma unroll
  for (int i = 0; i < 4; ++i)
    #pragma unroll
    for (int j = 0; j < 4; ++j) acc[i][j] = zero;

  for (int k0 = 0; k0 < Kdim; k0 += 32) {
    __syncthreads();
    #pragma unroll
    for (int it = 0; it < 2; ++it) {
      int cid = tid + it * 256;
      int r = cid >> 2, c = (cid & 3) * 8;
      uint4 va = *(const uint4*)(A  + (size_t)(m0 + r) * Kdim + k0 + c);
      *(uint4*)(&As[r * 40 + c]) = va;
      uint4 vb = *(const uint4*)(Bt + (size_t)(n0 + r) * Kdim + k0 + c);
      *(uint4*)(&Bs[r * 40 + c]) = vb;
    }
    __syncthreads();
    bf16x8 af[4], bfr[4];
    #pragma unroll
    for (int i = 0; i < 4; ++i)
      af[i] = *(const bf16x8*)(&As[(wm * 64 + i * 16 + lm) * 40 + lq * 8]);
    #pragma unroll
    for (int j = 0; j < 4; ++j)
      bfr[j] = *(const bf16x8*)(&Bs[(wn * 64 + j * 16 + lm) * 40 + lq * 8]);
    #pragma unroll
    for (int i = 0; i < 4; ++i)
      #pragma unroll
      for (int j = 0; j < 4; ++j)
        acc[i][j] = __builtin_amdgcn_mfma_f32_16x16x32_bf16(af[i], bfr[j], acc[i][j], 0, 0, 0);
  }

  int mbase = m0 + wm * 64, nbase = n0 + wn * 64;
  #pragma unroll
  for (int j = 0; j < 4; ++j) {
    int n = nbase + j * 16 + lm;
    float bv_ = bias[n];
    if (MODE == 0) {
      #pragma unroll
      for (int i = 0; i < 4; ++i)
        #pragma unroll
        for (int r = 0; r < 4; ++r) {
          int m = mbase + i * 16 + lq * 4 + r;
          C[(size_t)m * Ndim + n] = acc[i][j][r] + bv_;
        }
    } else {
      int which = n / 768;             // uniform per block (768 = 6*128)
      int rem = n - which * 768;
      int h = rem >> 6, e = rem & 63;
      float scl = (which == 0) ? QSCALE_LOG2E : 1.0f;
      if (which == 2) {
        #pragma unroll
        for (int i = 0; i < 4; ++i)
          #pragma unroll
          for (int r = 0; r < 4; ++r) {
            int m = mbase + i * 16 + lq * 4 + r;
            int b = m >> 11, s = m & 2047;
            Vo[((size_t)(b * H_ + h) * 64 + e) * S_ + s] = (bf16)(acc[i][j][r] + bv_);
          }
      } else {
        bf16* dst = (which == 0) ? Qo : Ko;
        #pragma unroll
        for (int i = 0; i < 4; ++i)
          #pragma unroll
          for (int r = 0; r < 4; ++r) {
            int m = mbase + i * 16 + lq * 4 + r;
            int b = m >> 11, s = m & 2047;
            dst[((size_t)(b * H_ + h) * S_ + s) * 64 + e] = (bf16)((acc[i][j][r] + bv_) * scl);
          }
      }
    }
  }
}

// ---------------------------------------------------------------------------
// Flash attention, register-resident P, no Q staging, double-buffered K/V,
// ONE barrier per kv-tile.
//  - Q B-frags loaded straight from global (loop-invariant, 4x16B/lane)
//  - S^T = K·Q^T (16x16x32); C-tiles == A-operand of 16x16x16 => O = P·V
//    with zero cross-lane traffic, P never leaves registers
//  - softmax numerator = exp2(QK) with log2e pre-folded into Q
//  - XCD swizzle: 12 whole (b,h) per XCD -> K/V L2-resident
// LDS: 2*(Ks 8704 + Vs 8704) = 34816 B -> 4 blocks/CU.
// ---------------------------------------------------------------------------
#define LST 68
#define KVBUF (64 * LST)   // elems per K or V buffer
__global__ __launch_bounds__(256, 4) void flash_attn(
    const bf16* __restrict__ Q, const bf16* __restrict__ K,
    const bf16* __restrict__ Vt, bf16* __restrict__ ctx)
{
  __shared__ bf16 Ks[2 * KVBUF];
  __shared__ bf16 Vs[2 * KVBUF];
  int tid = threadIdx.x;
  int wave = tid >> 6, lane = tid & 63;
  int lm = lane & 15, lq = lane >> 4;

  // XCD-aware decode: id%8 = XCD (round-robin dispatch); 12 (b,h) per XCD.
  int id = blockIdx.x;
  int xcd = id & 7, jj = id >> 3;
  int bh = xcd * 12 + (jj >> 4);
  int q0 = (jj & 15) * 128;

  const bf16* Qb = Q + (size_t)bh * S_ * 64;
  const bf16* Kb = K + (size_t)bh * S_ * 64;
  const bf16* Vb = Vt + (size_t)bh * 64 * S_;

  // Q B-operand frags straight from global: qf[ks][mi] =
  //   Q[q0 + wave*32 + mi*16 + lm][ks*32 + lq*8 .. +7]
  int qw = wave * 32;
  bf16x8 qf[2][2];
  #pragma unroll
  for (int ks = 0; ks < 2; ++ks)
    #pragma unroll
    for (int mi = 0; mi < 2; ++mi)
      qf[ks][mi] = *(const bf16x8*)(Qb + (size_t)(q0 + qw + mi * 16 + lm) * 64
                                       + ks * 32 + lq * 8);

  // K/V prefetch (tile 0)
  int pr[2], pc[2];
  uint4 pk[2], pv[2];
  #pragma unroll
  for (int it = 0; it < 2; ++it) {
    int cc = tid + it * 256;
    pr[it] = cc >> 3; pc[it] = (cc & 7) * 8;
    pk[it] = *(const uint4*)(Kb + (size_t)pr[it] * 64 + pc[it]);
    pv[it] = *(const uint4*)(Vb + (size_t)pr[it] * S_ + pc[it]);
  }

  f32x4 zero = {0.f, 0.f, 0.f, 0.f};
  f32x4 O[2][4];           // O[q = qw+mi*16+lq*4+r][d = dj*16+lm]
  float lsum[2] = {0.f, 0.f};
  #pragma unroll
  for (int i = 0; i < 2; ++i)
    #pragma unroll
    for (int d = 0; d < 4; ++d) O[i][d] = zero;

  for (int t = 0; t < S_ / 64; ++t) {
    int cur = (t & 1) * KVBUF;
    // store prefetched tile t into the idle buffer
    #pragma unroll
    for (int it = 0; it < 2; ++it) {
      *(uint4*)(&Ks[cur + pr[it] * LST + pc[it]]) = pk[it];   // Ks[kv][d]
      *(uint4*)(&Vs[cur + pr[it] * LST + pc[it]]) = pv[it];   // Vs[d][kv]
    }
    // prefetch tile t+1 into regs (floats with vmcnt across compute)
    if (t + 1 < S_ / 64) {
      int kvn = (t + 1) * 64;
      #pragma unroll
      for (int it = 0; it < 2; ++it) {
        pk[it] = *(const uint4*)(Kb + (size_t)(kvn + pr[it]) * 64 + pc[it]);
        pv[it] = *(const uint4*)(Vb + (size_t)pr[it] * S_ + kvn + pc[it]);
      }
    }
    __syncthreads();   // single barrier: buf[cur] now consistent for all waves

    // ---- S^T = K Q^T : sacc[mi][ni] = S^T[kv=ni*16+lq*4+r][q=qw+mi*16+lm]
    f32x4 sacc[2][4];
    #pragma unroll
    for (int i = 0; i < 2; ++i)
      #pragma unroll
      for (int j = 0; j < 4; ++j) sacc[i][j] = zero;
    #pragma unroll
    for (int ks = 0; ks < 2; ++ks) {
      #pragma unroll
      for (int ni = 0; ni < 4; ++ni) {
        bf16x8 ak = *(const bf16x8*)(&Ks[cur + (ni * 16 + lm) * LST + ks * 32 + lq * 8]);
        sacc[0][ni] = __builtin_amdgcn_mfma_f32_16x16x32_bf16(ak, qf[ks][0], sacc[0][ni], 0, 0, 0);
        sacc[1][ni] = __builtin_amdgcn_mfma_f32_16x16x32_bf16(ak, qf[ks][1], sacc[1][ni], 0, 0, 0);
      }
    }

    // ---- P = exp2(S): stays in registers (C-layout of S^T == A-layout of P)
    bf16x4 pexp[2][4];
    #pragma unroll
    for (int mi = 0; mi < 2; ++mi) {
      #pragma unroll
      for (int ni = 0; ni < 4; ++ni) {
        float e0 = EXP2F(sacc[mi][ni][0]);
        float e1 = EXP2F(sacc[mi][ni][1]);
        float e2 = EXP2F(sacc[mi][ni][2]);
        float e3 = EXP2F(sacc[mi][ni][3]);
        lsum[mi] += (e0 + e1) + (e2 + e3);
        bf16x4 px = {(bf16)e0, (bf16)e1, (bf16)e2, (bf16)e3};
        pexp[mi][ni] = px;
      }
    }

    // ---- O += P V : A = pexp (regs), B = V^T rows (b64 LDS reads)
    #pragma unroll
    for (int ni = 0; ni < 4; ++ni) {
      #pragma unroll
      for (int dj = 0; dj < 4; ++dj) {
        bf16x4 vb = *(const bf16x4*)(&Vs[cur + (dj * 16 + lm) * LST + ni * 16 + lq * 4]);
        O[0][dj] = mfma16(pexp[0][ni], vb, O[0][dj]);
        O[1][dj] = mfma16(pexp[1][ni], vb, O[1][dj]);
      }
    }
  }

  // ---- final row-sum reduction: combine the 4 kv-quad groups (lq dim)
  float ls[2];
  #pragma unroll
  for (int mi = 0; mi < 2; ++mi) {
    float rs = lsum[mi];
    rs += __shfl_xor(rs, 16);
    rs += __shfl_xor(rs, 32);
    ls[mi] = rs;   // valid for q = qw + mi*16 + lm
  }

  // ---- epilogue: ctx[b][s][h*64+d] = O / l
  int b = bh / H_, h = bh % H_;
  #pragma unroll
  for (int mi = 0; mi < 2; ++mi) {
    #pragma unroll
    for (int r = 0; r < 4; ++r) {
      int s = q0 + qw + mi * 16 + lq * 4 + r;
      float lv = __shfl(ls[mi], lq * 4 + r);   // held by lane lm' = lq*4+r
      float linv = 1.0f / lv;
      #pragma unroll
      for (int dj = 0; dj < 4; ++dj) {
        int d = dj * 16 + lm;
        ctx[(size_t)(b * S_ + s) * D_ + h * 64 + d] = (bf16)(O[mi][dj][r] * linv);
      }
    }
  }
}

// ---------------------------------------------------------------------------
extern "C" void kernel_launch(void* const* d_in, const int* in_sizes, int n_in,
                              void* d_out, int out_size, void* d_ws, size_t ws_size,
                              hipStream_t stream)
{
  const float* x  = (const float*)d_in[0];
  const float* Wq = (const float*)d_in[1];
  const float* bq = (const float*)d_in[2];
  const float* Wk = (const float*)d_in[3];
  const float* bk = (const float*)d_in[4];
  const float* Wv = (const float*)d_in[5];
  const float* bv = (const float*)d_in[6];
  const float* Wp = (const float*)d_in[7];
  const float* bp = (const float*)d_in[8];
  float* out = (float*)d_out;

  char* w = (char*)d_ws;
  const size_t SZ  = (size_t)BH_ * S_ * 64;   // 12,582,912 elems
  const size_t SZb = SZ * sizeof(bf16);       // 25,165,824 bytes
  bf16*  xb   = (bf16*)(w);                   // also reused as ctx
  bf16*  Qb   = (bf16*)(w + 1 * SZb);
  bf16*  Kb   = (bf16*)(w + 2 * SZb);
  bf16*  Vtb  = (bf16*)(w + 3 * SZb);
  bf16*  Wt   = (bf16*)(w + 4 * SZb);                       // [2304][768] bf16
  bf16*  Wpt  = (bf16*)(w + 4 * SZb + 2304 * 768 * 2);      // [768][768] bf16
  float* ball = (float*)(w + 4 * SZb + 2304 * 768 * 2 + 768 * 768 * 2);
  bf16*  ctx  = xb;  // xb's last reader (QKV gemm) precedes flash_attn on stream

  // prep
  f2b<<<(int)(SZ / (256 * 8)), 256, 0, stream>>>(x, xb, (int)SZ);
  transpose64_f2b<<<dim3(12, 1, 12), 256, 0, stream>>>(Wq, Wt,                      768, 64);
  transpose64_f2b<<<dim3(12, 1, 12), 256, 0, stream>>>(Wk, Wt + (size_t)768 * 768,  768, 64);
  transpose64_f2b<<<dim3(12, 1, 12), 256, 0, stream>>>(Wv, Wt + (size_t)1536 * 768, 768, 64);
  transpose64_f2b<<<dim3(12, 12, 1), 256, 0, stream>>>(Wp, Wpt, 768, 768);
  pack_bias<<<9, 256, 0, stream>>>(bq, bk, bv, ball);

  // QKV projection -> Q(scaled)/K [B,H,S,64], V -> V^T [bh][64][S] (+bias)
  gemm_bt<1><<<dim3(128, 18), 256, 0, stream>>>(xb, Wt, ball, (float*)nullptr,
                                                Qb, Kb, Vtb, M_, 2304, 768);
  // attention (1536 blocks, XCD-swizzled decode inside)
  flash_attn<<<1536, 256, 0, stream>>>(Qb, Kb, Vtb, ctx);
  // output projection -> fp32 out
  gemm_bt<0><<<dim3(128, 6), 256, 0, stream>>>(ctx, Wpt, bp, out,
                                               (bf16*)nullptr, (bf16*)nullptr, (bf16*)nullptr,
                                               M_, 768, 768);
}